// Round 17
// baseline (68.878 us; speedup 1.0000x reference)
//
#include <hip/hip_runtime.h>

// Problem: N=65536 rows, H=512, E=8, OUT=2.
//   oh=x[:,0:8], delta=x[:,8], phi=x[:,9]
//   h  = relu(delta*w1 + b1 + phi*(oh@meta_w) + oh@meta_b)   -> one K=32 bf16 MFMA GEMM
//   h2 = relu(h @ w2 + b2)                                   -> main GEMM, bf16 MFMA, K=512
//   out = h2 @ w3 + b3                                       -> fused shuffle-reduce epilogue
//
// R17: m201-style schedule. w2 K-slabs (32KB) staged into SHARED LDS by
// global_load_lds, TRIPLE-buffered, lead-2, COUNTED vmcnt(4) (never 0 in
// steady state), raw s_barrier (no __syncthreads drain in the K-loop),
// setprio(1) around the 16-MFMA cluster. Each wave stages 4KB (4 insts);
// vmcnt(4)+barrier => all waves' stage(t) landed => whole slab t valid.
// Buffer hazard: buf X written at iter t was last read at iter t-3; readers
// are 2 barriers past. bf consumption = LDS read (~120cy) -- L2 latency is
// off the critical path (R11-R16's invariant stall).
// LDS 64KB haug + 96KB bufs = 163840 exact; xls overlays buf2 (first DMA
// into buf2 is stage(2) at iter 0, after layer-1); oacc overlays buf0
// (used only after the final drain).

#define BM 64

typedef float f32x4 __attribute__((ext_vector_type(4)));
typedef short s16x8 __attribute__((ext_vector_type(8)));

__device__ __forceinline__ short f2bf(float f) {
    union { float f; unsigned u; } c; c.f = f;
    unsigned u = c.u;
    return (short)((u + 0x7FFFu + ((u >> 16) & 1u)) >> 16);  // RNE
}

__device__ __forceinline__ void gload16(const void* g, void* l) {
    __builtin_amdgcn_global_load_lds(
        (const __attribute__((address_space(1))) void*)g,
        (__attribute__((address_space(3))) void*)l, 16, 0, 0);
}

// ---------------- prep: build bf16 weight images in workspace ----------------
// w2s layout: [ks=16][g=4][n=512][j=8] bf16  (B-fragment order; one 32KB slab
//   per K-step ks, internally [g][n][j])
// waugS layout: [col=512][k=32] bf16, rows of W' = [meta_w(8); meta_b(8); w1; b1; 0...]
__global__ void prep_kernel(const float* __restrict__ w1, const float* __restrict__ b1,
                            const float* __restrict__ mw, const float* __restrict__ mb,
                            const float* __restrict__ w2,
                            short* __restrict__ w2s, short* __restrict__ waugS) {
    int id = blockIdx.x * 256 + threadIdx.x;
    if (id < 512 * 512) {
        int k = id / 512, n = id % 512;
        int ks = k >> 5, g = (k >> 3) & 3, j = k & 7;
        w2s[(((ks * 4 + g) * 512) + n) * 8 + j] = f2bf(w2[id]);
    }
    if (id < 512 * 32) {
        int col = id >> 5, k = id & 31;
        float v = 0.f;
        if (k < 8)        v = mw[k * 512 + col];
        else if (k < 16)  v = mb[(k - 8) * 512 + col];
        else if (k == 16) v = w1[col];
        else if (k == 17) v = b1[col];
        waugS[col * 32 + k] = f2bf(v);
    }
}

// ---------------- fused MLP ----------------
// grid 1024 blocks x 512 threads (8 waves). Block tile: 64 rows x 512 cols.
// Wave w owns cols [w*64, w*64+64), all 64 rows -> acc 4(m) x 4(n) frags.
__global__ __launch_bounds__(512) void fused_mlp(
    const float* __restrict__ x, const short* __restrict__ waugS,
    const short* __restrict__ w2s, const float* __restrict__ b2,
    const float* __restrict__ w3, const float* __restrict__ b3,
    float* __restrict__ out) {

    __shared__ __align__(16) char Lall[163840];
    short* haug = (short*)Lall;          // 64KB: h frag-order, idx=(k>>3)*512+row*8+(k&7)
    char*  bufs = Lall + 65536;          // 3 x 32KB staged w2 slabs

    const int tid  = threadIdx.x;
    const int wv   = tid >> 6;           // 0..7
    const int lane = tid & 63;
    const int l15  = lane & 15;
    const int g    = lane >> 4;
    const long rowbase = (long)blockIdx.x * BM;

    float* xls  = (float*)(bufs + 2 * 32768);   // overlay buf2 (dead until stage(2))
    float* oacc = (float*)(bufs);               // overlay buf0 (epilogue only)

    // staging: wave wv copies slab bytes [wv*4096, wv*4096+4096) linearly.
    // src per-lane, dst wave-uniform (gload_lds auto lane*16 offset).
    const char* srcS = (const char*)w2s + wv * 4096 + lane * 16;
    char* dst0 = bufs + 0 * 32768 + wv * 4096;
    char* dst1 = bufs + 1 * 32768 + wv * 4096;
    char* dst2 = bufs + 2 * 32768 + wv * 4096;

#define STAGE(T, DST)                                        \
    do {                                                     \
        const char* s_ = srcS + (size_t)(T) * 32768;         \
        gload16(s_,        (DST));                           \
        gload16(s_ + 1024, (DST) + 1024);                    \
        gload16(s_ + 2048, (DST) + 2048);                    \
        gload16(s_ + 3072, (DST) + 3072);                    \
    } while (0)

    // prologue: slabs 0,1 in flight during x-load + layer-1
    STAGE(0, dst0);
    STAGE(1, dst1);

    // ---- load x tile (64x10 f32 = 640 floats) ----
    for (int i = tid; i < BM * 10; i += 512) xls[i] = x[rowbase * 10 + i];
    __syncthreads();

    // ---- layer 1: one K=32 MFMA pass; h -> LDS in fragment order ----
    {
        s16x8 afr[4];
#pragma unroll
        for (int m = 0; m < 4; ++m) {
            int r = m * 16 + l15;
            float v[8];
            if (g == 0) {                    // k=0..7 : oh * phi
                float phi = xls[r * 10 + 9];
#pragma unroll
                for (int j = 0; j < 8; ++j) v[j] = xls[r * 10 + j] * phi;
            } else if (g == 1) {             // k=8..15 : oh
#pragma unroll
                for (int j = 0; j < 8; ++j) v[j] = xls[r * 10 + j];
            } else if (g == 2) {             // k=16,17 : delta, 1
                v[0] = xls[r * 10 + 8]; v[1] = 1.f;
#pragma unroll
                for (int j = 2; j < 8; ++j) v[j] = 0.f;
            } else {                         // k=24..31 : 0
#pragma unroll
                for (int j = 0; j < 8; ++j) v[j] = 0.f;
            }
            s16x8 a;
#pragma unroll
            for (int j = 0; j < 8; ++j) a[j] = f2bf(v[j]);
            afr[m] = a;
        }
#pragma unroll
        for (int nf = 0; nf < 4; ++nf) {
            int col = wv * 64 + nf * 16 + l15;
            s16x8 bfr = *(const s16x8*)(waugS + col * 32 + g * 8);
            int chi = (col >> 3) * 512 + (col & 7);
#pragma unroll
            for (int m = 0; m < 4; ++m) {
                f32x4 c = {0.f, 0.f, 0.f, 0.f};
                c = __builtin_amdgcn_mfma_f32_16x16x32_bf16(afr[m], bfr, c, 0, 0, 0);
#pragma unroll
                for (int r4 = 0; r4 < 4; ++r4) {
                    int row = m * 16 + g * 4 + r4;
                    float hv = c[r4];
                    hv = hv > 0.f ? hv : 0.f;
                    haug[chi + row * 8] = f2bf(hv);
                }
            }
        }
    }
    __syncthreads();   // h ready (this also drains prologue stages 0,1 -- ok, once)

    // ---- layer 2: K=512, 16 iters; shared triple-buffer, counted vmcnt ----
    f32x4 acc[4][4];
#pragma unroll
    for (int m = 0; m < 4; ++m)
#pragma unroll
        for (int n = 0; n < 4; ++n) acc[m][n] = (f32x4){0.f, 0.f, 0.f, 0.f};

    const char* hb  = (const char*)haug + g * 1024 + l15 * 16;              // +T*4096+m*256
    const char* bp0 = bufs + 0 * 32768 + g * 8192 + (wv * 64 + l15) * 16;   // +n*256
    const char* bp1 = bufs + 1 * 32768 + g * 8192 + (wv * 64 + l15) * 16;
    const char* bp2 = bufs + 2 * 32768 + g * 8192 + (wv * 64 + l15) * 16;

#define ITER(T, BP, DSTN, DOSTAGE, WN)                                                       \
    do {                                                                                     \
        asm volatile("s_waitcnt vmcnt(" WN ")" ::: "memory");                                \
        __builtin_amdgcn_sched_barrier(0);                                                   \
        __builtin_amdgcn_s_barrier();   /* slab T valid everywhere; buf (T+2)%3 free */      \
        s16x8 bq0 = *(const s16x8*)((BP));                                                   \
        s16x8 bq1 = *(const s16x8*)((BP) + 256);                                             \
        s16x8 bq2 = *(const s16x8*)((BP) + 512);                                             \
        s16x8 bq3 = *(const s16x8*)((BP) + 768);                                             \
        s16x8 aq0 = *(const s16x8*)(hb + (T) * 4096);                                        \
        s16x8 aq1 = *(const s16x8*)(hb + (T) * 4096 + 256);                                  \
        s16x8 aq2 = *(const s16x8*)(hb + (T) * 4096 + 512);                                  \
        s16x8 aq3 = *(const s16x8*)(hb + (T) * 4096 + 768);                                  \
        if (DOSTAGE) STAGE((T) + 2, DSTN);  /* issue under ds_read latency */                \
        asm volatile("s_waitcnt lgkmcnt(0)" ::: "memory");                                   \
        __builtin_amdgcn_sched_barrier(0);                                                   \
        __builtin_amdgcn_s_setprio(1);                                                       \
        acc[0][0] = __builtin_amdgcn_mfma_f32_16x16x32_bf16(aq0, bq0, acc[0][0], 0, 0, 0);   \
        acc[0][1] = __builtin_amdgcn_mfma_f32_16x16x32_bf16(aq0, bq1, acc[0][1], 0, 0, 0);   \
        acc[0][2] = __builtin_amdgcn_mfma_f32_16x16x32_bf16(aq0, bq2, acc[0][2], 0, 0, 0);   \
        acc[0][3] = __builtin_amdgcn_mfma_f32_16x16x32_bf16(aq0, bq3, acc[0][3], 0, 0, 0);   \
        acc[1][0] = __builtin_amdgcn_mfma_f32_16x16x32_bf16(aq1, bq0, acc[1][0], 0, 0, 0);   \
        acc[1][1] = __builtin_amdgcn_mfma_f32_16x16x32_bf16(aq1, bq1, acc[1][1], 0, 0, 0);   \
        acc[1][2] = __builtin_amdgcn_mfma_f32_16x16x32_bf16(aq1, bq2, acc[1][2], 0, 0, 0);   \
        acc[1][3] = __builtin_amdgcn_mfma_f32_16x16x32_bf16(aq1, bq3, acc[1][3], 0, 0, 0);   \
        acc[2][0] = __builtin_amdgcn_mfma_f32_16x16x32_bf16(aq2, bq0, acc[2][0], 0, 0, 0);   \
        acc[2][1] = __builtin_amdgcn_mfma_f32_16x16x32_bf16(aq2, bq1, acc[2][1], 0, 0, 0);   \
        acc[2][2] = __builtin_amdgcn_mfma_f32_16x16x32_bf16(aq2, bq2, acc[2][2], 0, 0, 0);   \
        acc[2][3] = __builtin_amdgcn_mfma_f32_16x16x32_bf16(aq2, bq3, acc[2][3], 0, 0, 0);   \
        acc[3][0] = __builtin_amdgcn_mfma_f32_16x16x32_bf16(aq3, bq0, acc[3][0], 0, 0, 0);   \
        acc[3][1] = __builtin_amdgcn_mfma_f32_16x16x32_bf16(aq3, bq1, acc[3][1], 0, 0, 0);   \
        acc[3][2] = __builtin_amdgcn_mfma_f32_16x16x32_bf16(aq3, bq2, acc[3][2], 0, 0, 0);   \
        acc[3][3] = __builtin_amdgcn_mfma_f32_16x16x32_bf16(aq3, bq3, acc[3][3], 0, 0, 0);   \
        __builtin_amdgcn_s_setprio(0);                                                       \
    } while (0)

    ITER(0,  bp0, dst2, 1, "4");
    ITER(1,  bp1, dst0, 1, "4");
    ITER(2,  bp2, dst1, 1, "4");
    ITER(3,  bp0, dst2, 1, "4");
    ITER(4,  bp1, dst0, 1, "4");
    ITER(5,  bp2, dst1, 1, "4");
    ITER(6,  bp0, dst2, 1, "4");
    ITER(7,  bp1, dst0, 1, "4");
    ITER(8,  bp2, dst1, 1, "4");
    ITER(9,  bp0, dst2, 1, "4");
    ITER(10, bp1, dst0, 1, "4");
    ITER(11, bp2, dst1, 1, "4");
    ITER(12, bp0, dst2, 1, "4");
    ITER(13, bp1, dst0, 1, "4");   // stages slab 15 -> buf0
    ITER(14, bp2, dst2, 0, "4");
    ITER(15, bp0, dst0, 0, "0");

#undef ITER
#undef STAGE

    // ---- layer 3: relu(acc+b2) @ w3, per-(m,r4) immediate reduce ----
    __syncthreads();                 // full drain; bufs dead
    if (tid < 128) oacc[tid] = 0.f;  // oacc overlays buf0
    __syncthreads();

    float bb2[4], w30[4], w31[4];
#pragma unroll
    for (int n = 0; n < 4; ++n) {
        int col = wv * 64 + n * 16 + l15;
        bb2[n] = b2[col];
        w30[n] = w3[col * 2 + 0];
        w31[n] = w3[col * 2 + 1];
    }
#pragma unroll
    for (int m = 0; m < 4; ++m) {
#pragma unroll
        for (int r4 = 0; r4 < 4; ++r4) {
            float s0 = 0.f, s1 = 0.f;
#pragma unroll
            for (int n = 0; n < 4; ++n) {
                float v = acc[m][n][r4] + bb2[n];
                v = v > 0.f ? v : 0.f;
                s0 += v * w30[n];
                s1 += v * w31[n];
            }
            s0 += __shfl_xor(s0, 1); s1 += __shfl_xor(s1, 1);
            s0 += __shfl_xor(s0, 2); s1 += __shfl_xor(s1, 2);
            s0 += __shfl_xor(s0, 4); s1 += __shfl_xor(s1, 4);
            s0 += __shfl_xor(s0, 8); s1 += __shfl_xor(s1, 8);
            if (l15 == 0) {
                int row = m * 16 + g * 4 + r4;
                atomicAdd(&oacc[row * 2 + 0], s0);
                atomicAdd(&oacc[row * 2 + 1], s1);
            }
        }
    }
    __syncthreads();

    if (tid < 128) {
        int row = tid >> 1, o = tid & 1;
        out[(rowbase + row) * 2 + o] = oacc[tid] + b3[o];
    }
}

extern "C" void kernel_launch(void* const* d_in, const int* in_sizes, int n_in,
                              void* d_out, int out_size, void* d_ws, size_t ws_size,
                              hipStream_t stream) {
    const float* x  = (const float*)d_in[0];
    const float* w1 = (const float*)d_in[1];
    const float* b1 = (const float*)d_in[2];
    const float* mw = (const float*)d_in[3];
    const float* mb = (const float*)d_in[4];
    const float* w2 = (const float*)d_in[5];
    const float* b2 = (const float*)d_in[6];
    const float* w3 = (const float*)d_in[7];
    const float* b3 = (const float*)d_in[8];
    float* out = (float*)d_out;

    short* w2s   = (short*)d_ws;          // 512 KB
    short* waugS = w2s + 512 * 512;       // 32 KB

    prep_kernel<<<1024, 256, 0, stream>>>(w1, b1, mw, mb, w2, w2s, waugS);
    fused_mlp<<<65536 / BM, 512, 0, stream>>>(x, waugS, w2s, b2, w3, b3, out);
}